// Round 1
// baseline (285.160 us; speedup 1.0000x reference)
//
#include <hip/hip_runtime.h>

#define NPOS 225
#define FSTR 227   // odd LDS stride: breaks pow2 bank patterns

// ---- quantization helpers (all scales are powers of two -> exact mul) ----
__device__ __forceinline__ float qw8(float w) {           // int8 weight, scale 128, round-half-even
  return rintf(fminf(fmaxf(w * 128.f, -128.f), 127.f)) * 0.0078125f;
}
__device__ __forceinline__ float qb32(float b) {          // int32 bias, scale 128*128
  return rintf(b * 16384.f) * 6.103515625e-05f;
}
__device__ __forceinline__ float fq8f(float v) {          // fake_quant(.,128,8,floor=True)
  return floorf(fminf(fmaxf(v * 128.f, -128.f), 127.f)) * 0.0078125f;
}
__device__ __forceinline__ float qdir(float v) {          // clip(+-16) then fake_quant(.,32,16)
  return rintf(fminf(fmaxf(v, -16.f), 16.f) * 32.f) * 0.03125f;
}

__global__ __launch_bounds__(256, 2)
void nnue_fused(const int* __restrict__ line,
                const float* __restrict__ emb,
                const float* __restrict__ dw_w,  const float* __restrict__ dw_b,
                const float* __restrict__ pw1_w, const float* __restrict__ pw1_b,
                const float* __restrict__ pw2_w, const float* __restrict__ pw2_b,
                const float* __restrict__ pout_w,const float* __restrict__ pout_b,
                const float* __restrict__ su1w,  const float* __restrict__ su1b,
                const float* __restrict__ su2w,  const float* __restrict__ su2b,
                const float* __restrict__ sdw,   const float* __restrict__ sdb,
                const float* __restrict__ vl1w,  const float* __restrict__ vl1b,
                const float* __restrict__ vl2w,  const float* __restrict__ vl2b,
                const float* __restrict__ vl3w,  const float* __restrict__ vl3b,
                float* __restrict__ out)
{
  __shared__ float fbuf[64 * FSTR];   // f / feature, layout [c][p], 58112 B
  __shared__ float sreg[9 * 64];      // quantized region sums
  __shared__ float sfsum[64];         // quantized feature_sum
  __shared__ float shh[64];           // policy hidden
  __shared__ float sobuf[528];        // policy o
  __shared__ float spwq[512];         // quantized dynamic pw [16][32]
  __shared__ float hstar[9 * 64];     // star mid
  __shared__ float vstar[9 * 64];     // star out (v)
  __shared__ float squads[4 * 64];
  __shared__ float shq[4 * 64];
  __shared__ float svq[4 * 64];       // vq
  __shared__ float sv1[64];
  __shared__ float sv2[64];

  const int tid  = threadIdx.x;
  const int b    = blockIdx.x;
  const int wid  = tid >> 6;
  const int lane = tid & 63;
  const int* le  = line + b * 4 * NPOS;

  // ---------- Phase 1: gather + per-dir quant + mean + relu -> fbuf[c][p] ----------
  // wave handles positions p = wid + 4k, two per iteration (8 row-loads in flight)
  for (int p = wid; p < NPOS; p += 8) {
    const int p2 = p + 4;
    const bool h2 = (p2 < NPOS);
    int i0 = le[p], i1 = le[NPOS + p], i2 = le[2 * NPOS + p], i3 = le[3 * NPOS + p];
    int j0 = i0, j1 = i1, j2 = i2, j3 = i3;
    if (h2) { j0 = le[p2]; j1 = le[NPOS + p2]; j2 = le[2 * NPOS + p2]; j3 = le[3 * NPOS + p2]; }
    float a0 = emb[i0 * 64 + lane], a1 = emb[i1 * 64 + lane];
    float a2 = emb[i2 * 64 + lane], a3 = emb[i3 * 64 + lane];
    float c0 = emb[j0 * 64 + lane], c1 = emb[j1 * 64 + lane];
    float c2 = emb[j2 * 64 + lane], c3 = emb[j3 * 64 + lane];
    fbuf[lane * FSTR + p] = fmaxf((qdir(a0) + qdir(a1) + qdir(a2) + qdir(a3)) * 0.25f, 0.f);
    if (h2)
      fbuf[lane * FSTR + p2] = fmaxf((qdir(c0) + qdir(c1) + qdir(c2) + qdir(c3)) * 0.25f, 0.f);
  }
  __syncthreads();

  // ---------- Phase 2: depthwise 3x3 conv on channels 0..31 (x = 4*f exactly) ----------
  {
    const int cc = tid >> 3;   // channel 0..31
    const int pg = tid & 7;    // position group
    float wq9[9];
#pragma unroll
    for (int t = 0; t < 9; ++t)
      wq9[t] = rintf(fminf(fmaxf(dw_w[cc * 9 + t] * 65536.f, -32768.f), 32767.f)) * 1.52587890625e-05f;
    const float bq = rintf(fminf(fmaxf(dw_b[cc] * 128.f, -32768.f), 32767.f)) * 0.0078125f;
    float outr[29];
#pragma unroll
    for (int k = 0; k < 29; ++k) {
      const int p = pg + 8 * k;
      if (p < NPOS) {
        const int y0 = p / 15, x0 = p - y0 * 15;
        float s = 0.f;
#pragma unroll
        for (int dy = 0; dy < 3; ++dy)
#pragma unroll
          for (int dx = 0; dx < 3; ++dx) {
            const int y = y0 + dy - 1, x = x0 + dx - 1;
            float xv = 0.f;
            if ((unsigned)y < 15u && (unsigned)x < 15u) xv = 4.f * fbuf[cc * FSTR + y * 15 + x];
            s += floorf(xv * wq9[dy * 3 + dx] * 128.f) * 0.0078125f;  // fq(.,128,32,floor)
          }
        s = fmaxf(s + bq, 0.f);
        outr[k] = fminf(s, 255.9921875f);  // fq(conv,128,16): exact rint + upper clip
      } else outr[k] = 0.f;
    }
    __syncthreads();   // all conv reads done before overwrite
#pragma unroll
    for (int k = 0; k < 29; ++k) {
      const int p = pg + 8 * k;
      if (p < NPOS) fbuf[cc * FSTR + p] = outr[k];
    }
  }
  __syncthreads();
  // fbuf now holds `feature` exactly (c>=32 channels: fq is identity on f)

  // ---------- Phase 3: global + 3x3 regional sums (exact integer sums) ----------
  if (tid < 64) {
    float tot = 0.f;
#pragma unroll
    for (int rh = 0; rh < 3; ++rh)
#pragma unroll
      for (int rw = 0; rw < 3; ++rw) {
        float rs = 0.f;
        for (int y = rh * 5; y < rh * 5 + 5; ++y)
          for (int x = rw * 5; x < rw * 5 + 5; ++x)
            rs += fbuf[tid * FSTR + y * 15 + x];
        sreg[(rh * 3 + rw) * 64 + tid] = floorf(rs * 4.f) * 0.0078125f;   // fq(sum/32,128,32,floor)
        tot += rs;
      }
    sfsum[tid] = floorf(tot * 0.5f) * 0.0078125f;                         // fq(sum/256,128,32,floor)
  }
  __syncthreads();

  // ---------- Phase 4: policy MLP (h, o, quantized dynamic weights) ----------
  if (tid < 64) {
    const float4* wr = (const float4*)(pw1_w + tid * 64);
    float acc = 0.f;
#pragma unroll
    for (int c4 = 0; c4 < 16; ++c4) {
      float4 w = wr[c4];
      acc += sfsum[c4 * 4 + 0] * qw8(w.x);
      acc += sfsum[c4 * 4 + 1] * qw8(w.y);
      acc += sfsum[c4 * 4 + 2] * qw8(w.z);
      acc += sfsum[c4 * 4 + 3] * qw8(w.w);
    }
    acc += qb32(pw1_b[tid]);
    shh[tid] = fmaxf(acc, 0.f);
  }
  __syncthreads();
  for (int j = tid; j < 528; j += 256) {
    const float4* wr = (const float4*)(pw2_w + j * 64);
    float acc = 0.f;
#pragma unroll
    for (int c4 = 0; c4 < 16; ++c4) {
      float4 w = wr[c4];
      acc += shh[c4 * 4 + 0] * qw8(w.x);
      acc += shh[c4 * 4 + 1] * qw8(w.y);
      acc += shh[c4 * 4 + 2] * qw8(w.z);
      acc += shh[c4 * 4 + 3] * qw8(w.w);
    }
    acc += qb32(pw2_b[j]);
    sobuf[j] = acc;
    if (j < 512)   // fq(o,128*128,16,floor)
      spwq[j] = floorf(fminf(fmaxf(acc * 16384.f, -32768.f), 32767.f)) * 6.103515625e-05f;
  }
  __syncthreads();

  // ---------- Phase 5: per-pixel dynamic pointwise conv + policy reduce ----------
  if (tid < NPOS) {
    float pinv[32];
#pragma unroll
    for (int c = 0; c < 32; ++c) pinv[c] = fbuf[c * FSTR + tid];   // pin == feature[:32] exactly
    float acc = 0.f;
#pragma unroll
    for (int i = 0; i < 16; ++i) {
      float s = 0.f;
#pragma unroll
      for (int c = 0; c < 32; ++c) s += pinv[c] * spwq[i * 32 + c];
      s = fmaxf(s + sobuf[512 + i], 0.f);
      acc += s * pout_w[i];
    }
    out[1536 + b * NPOS + tid] = acc + pout_b[0];
  }

  // ---------- Phase 6: 9-region star block (corners/edges/center share weights) ----------
  {
    const int g = tid >> 6;
    const int d = tid & 63;
    int ty, rA, rB, rC, rD;
    if (g == 0)      { ty = 0; rA = 0; rB = 2; rC = 6; rD = 8; }   // corners
    else if (g == 1) { ty = 1; rA = 1; rB = 3; rC = 5; rD = 7; }   // edges
    else             { ty = 2; rA = 4; rB = 4; rC = 4; rD = 4; }   // center (dup, benign)
    const float4* w1r = (const float4*)(su1w + ty * 4096 + d * 64);
    const float4* w2r = (const float4*)(su2w + ty * 4096 + d * 64);
    float aA1 = 0, aB1 = 0, aC1 = 0, aD1 = 0, aA2 = 0, aB2 = 0, aC2 = 0, aD2 = 0;
#pragma unroll 4
    for (int c4 = 0; c4 < 16; ++c4) {
      float4 w1 = w1r[c4], w2 = w2r[c4];
      float q1[4] = {qw8(w1.x), qw8(w1.y), qw8(w1.z), qw8(w1.w)};
      float q2[4] = {qw8(w2.x), qw8(w2.y), qw8(w2.z), qw8(w2.w)};
#pragma unroll
      for (int u = 0; u < 4; ++u) {
        const int c = c4 * 4 + u;
        float xA = sreg[rA * 64 + c], xB = sreg[rB * 64 + c];
        float xC = sreg[rC * 64 + c], xD = sreg[rD * 64 + c];
        aA1 += xA * q1[u]; aB1 += xB * q1[u]; aC1 += xC * q1[u]; aD1 += xD * q1[u];
        aA2 += xA * q2[u]; aB2 += xB * q2[u]; aC2 += xC * q2[u]; aD2 += xD * q2[u];
      }
    }
    const float bb1 = qb32(su1b[ty * 64 + d]);
    const float bb2 = qb32(su2b[ty * 64 + d]);
    hstar[rA * 64 + d] = fmaxf(aA1 + bb1, 0.f) * (aA2 + bb2);
    hstar[rB * 64 + d] = fmaxf(aB1 + bb1, 0.f) * (aB2 + bb2);
    hstar[rC * 64 + d] = fmaxf(aC1 + bb1, 0.f) * (aC2 + bb2);
    hstar[rD * 64 + d] = fmaxf(aD1 + bb1, 0.f) * (aD2 + bb2);
    __syncthreads();
    const float4* wdr = (const float4*)(sdw + ty * 4096 + d * 64);
    float dA = 0, dB = 0, dC = 0, dD = 0;
#pragma unroll 4
    for (int c4 = 0; c4 < 16; ++c4) {
      float4 w = wdr[c4];
      float q[4] = {qw8(w.x), qw8(w.y), qw8(w.z), qw8(w.w)};
#pragma unroll
      for (int u = 0; u < 4; ++u) {
        const int c = c4 * 4 + u;
        dA += hstar[rA * 64 + c] * q[u]; dB += hstar[rB * 64 + c] * q[u];
        dC += hstar[rC * 64 + c] * q[u]; dD += hstar[rD * 64 + c] * q[u];
      }
    }
    const float bd = qb32(sdb[ty * 64 + d]);
    vstar[rA * 64 + d] = dA + bd;
    vstar[rB * 64 + d] = dB + bd;
    vstar[rC * 64 + d] = dC + bd;
    vstar[rD * 64 + d] = dD + bd;
  }
  __syncthreads();

  // ---------- Phase 7: quad averaging (exact fixed-point chain) ----------
  {
    const int g = tid >> 6, d = tid & 63;
    int r0, r1, r2v, r3v;
    if (g == 0)      { r0 = 0; r1 = 1; r2v = 3; r3v = 4; }
    else if (g == 1) { r0 = 1; r1 = 2; r2v = 4; r3v = 5; }
    else if (g == 2) { r0 = 3; r1 = 4; r2v = 6; r3v = 7; }
    else             { r0 = 4; r1 = 5; r2v = 7; r3v = 8; }
    float a  = fq8f(vstar[r0 * 64 + d]);
    float bb = fq8f(vstar[r1 * 64 + d]);
    float cc = fq8f(vstar[r2v * 64 + d]);
    float dd = fq8f(vstar[r3v * 64 + d]);
    float ab = fq8f((a + bb + 0.0078125f) * 0.5f);
    float cd = fq8f((cc + dd + 0.0078125f) * 0.5f);
    squads[g * 64 + d] = fq8f((ab + cd + 0.0078125f) * 0.5f);
  }
  __syncthreads();

  // ---------- Phase 8: quad star block (type 3) ----------
  {
    const int g = tid >> 6, d = tid & 63;
    const float4* w1r = (const float4*)(su1w + 3 * 4096 + d * 64);
    const float4* w2r = (const float4*)(su2w + 3 * 4096 + d * 64);
    float a1 = 0.f, a2 = 0.f;
#pragma unroll 4
    for (int c4 = 0; c4 < 16; ++c4) {
      float4 w1 = w1r[c4], w2 = w2r[c4];
      float q1[4] = {qw8(w1.x), qw8(w1.y), qw8(w1.z), qw8(w1.w)};
      float q2[4] = {qw8(w2.x), qw8(w2.y), qw8(w2.z), qw8(w2.w)};
#pragma unroll
      for (int u = 0; u < 4; ++u) {
        float xq = squads[g * 64 + c4 * 4 + u];
        a1 += xq * q1[u];
        a2 += xq * q2[u];
      }
    }
    shq[g * 64 + d] = fmaxf(a1 + qb32(su1b[192 + d]), 0.f) * (a2 + qb32(su2b[192 + d]));
    __syncthreads();
    const float4* wdr = (const float4*)(sdw + 3 * 4096 + d * 64);
    float ad = 0.f;
#pragma unroll 4
    for (int c4 = 0; c4 < 16; ++c4) {
      float4 w = wdr[c4];
      float q[4] = {qw8(w.x), qw8(w.y), qw8(w.z), qw8(w.w)};
#pragma unroll
      for (int u = 0; u < 4; ++u) ad += shq[g * 64 + c4 * 4 + u] * q[u];
    }
    svq[g * 64 + d] = ad + qb32(sdb[192 + d]);
  }
  __syncthreads();

  // ---------- Phase 9: value MLP [320]->64->64->3 ----------
  if (tid < 64) {
    const float4* wr = (const float4*)(vl1w + tid * 320);
    float acc = 0.f;
#pragma unroll 4
    for (int k4 = 0; k4 < 16; ++k4) {
      float4 w = wr[k4];
      acc += sfsum[k4 * 4 + 0] * qw8(w.x);
      acc += sfsum[k4 * 4 + 1] * qw8(w.y);
      acc += sfsum[k4 * 4 + 2] * qw8(w.z);
      acc += sfsum[k4 * 4 + 3] * qw8(w.w);
    }
#pragma unroll 4
    for (int k4 = 16; k4 < 80; ++k4) {
      float4 w = wr[k4];
      const int base = k4 * 4 - 64;
      acc += svq[base + 0] * qw8(w.x);
      acc += svq[base + 1] * qw8(w.y);
      acc += svq[base + 2] * qw8(w.z);
      acc += svq[base + 3] * qw8(w.w);
    }
    acc += qb32(vl1b[tid]);
    sv1[tid] = fmaxf(acc, 0.f);
  }
  __syncthreads();
  if (tid < 64) {
    const float4* wr = (const float4*)(vl2w + tid * 64);
    float acc = 0.f;
#pragma unroll 4
    for (int k4 = 0; k4 < 16; ++k4) {
      float4 w = wr[k4];
      acc += sv1[k4 * 4 + 0] * qw8(w.x);
      acc += sv1[k4 * 4 + 1] * qw8(w.y);
      acc += sv1[k4 * 4 + 2] * qw8(w.z);
      acc += sv1[k4 * 4 + 3] * qw8(w.w);
    }
    acc += qb32(vl2b[tid]);
    sv2[tid] = fmaxf(acc, 0.f);
  }
  __syncthreads();
  if (tid < 3) {
    const float* wr = vl3w + tid * 64;
    float acc = 0.f;
#pragma unroll
    for (int k = 0; k < 64; ++k) acc += sv2[k] * qw8(wr[k]);
    out[b * 3 + tid] = acc + qb32(vl3b[tid]);
  }
}

extern "C" void kernel_launch(void* const* d_in, const int* in_sizes, int n_in,
                              void* d_out, int out_size, void* d_ws, size_t ws_size,
                              hipStream_t stream) {
  (void)in_sizes; (void)n_in; (void)out_size; (void)d_ws; (void)ws_size;
  nnue_fused<<<512, 256, 0, stream>>>(
      (const int*)d_in[0],  (const float*)d_in[1],
      (const float*)d_in[2],  (const float*)d_in[3],
      (const float*)d_in[4],  (const float*)d_in[5],
      (const float*)d_in[6],  (const float*)d_in[7],
      (const float*)d_in[8],  (const float*)d_in[9],
      (const float*)d_in[10], (const float*)d_in[11],
      (const float*)d_in[12], (const float*)d_in[13],
      (const float*)d_in[14], (const float*)d_in[15],
      (const float*)d_in[16], (const float*)d_in[17],
      (const float*)d_in[18], (const float*)d_in[19],
      (const float*)d_in[20], (const float*)d_in[21],
      (float*)d_out);
}

// Round 2
// 260.138 us; speedup vs baseline: 1.0962x; 1.0962x over previous
//
#include <hip/hip_runtime.h>

#define NPOS 225
#define FSTR 226   // ushort stride: byte stride 452 -> dword stride 113 (odd) -> conflict-free

// ---- workspace layout (float words unless noted) ----
#define OFF_PW1Q 0
#define OFF_PW2Q 4096
#define OFF_SU1Q 37888
#define OFF_SU2Q 54272
#define OFF_SDQ  70656
#define OFF_VL1Q 87040
#define OFF_VL2Q 107520
#define OFF_VL3Q 111616
#define OFF_PW1B 111808
#define OFF_PW2B 111872
#define OFF_SU1B 112400
#define OFF_SU2B 112656
#define OFF_SDB  112912
#define OFF_VL1B 113168
#define OFF_VL2B 113232
#define OFF_VL3B 113296
#define OFF_DWW  113300   // 288 ints (dwconv weights * 65536, int16 range)
#define OFF_DWB  113588   // 32 ints  (dwconv bias * 128, int16 range)
#define WS_TOTAL 113620

__device__ __forceinline__ float qw8(float w) {           // int8 weight, scale 128, half-even
  return rintf(fminf(fmaxf(w * 128.f, -128.f), 127.f)) * 0.0078125f;
}
__device__ __forceinline__ float qb32(float b) {          // int32 bias, scale 128*128
  return rintf(b * 16384.f) * 6.103515625e-05f;
}
__device__ __forceinline__ float fq8f(float v) {          // fake_quant(.,128,8,floor=True)
  return floorf(fminf(fmaxf(v * 128.f, -128.f), 127.f)) * 0.0078125f;
}
__device__ __forceinline__ float qd32(float v) {          // rint(clip(v,+-16)*32): value*32, integer-valued
  return rintf(fminf(fmaxf(v, -16.f), 16.f) * 32.f);
}

// ---------------- prep: quantize all static weights once ----------------
__global__ void nnue_prep(const float* __restrict__ pw1_w, const float* __restrict__ pw1_b,
                          const float* __restrict__ pw2_w, const float* __restrict__ pw2_b,
                          const float* __restrict__ su1w,  const float* __restrict__ su1b,
                          const float* __restrict__ su2w,  const float* __restrict__ su2b,
                          const float* __restrict__ sdw,   const float* __restrict__ sdb,
                          const float* __restrict__ vl1w,  const float* __restrict__ vl1b,
                          const float* __restrict__ vl2w,  const float* __restrict__ vl2b,
                          const float* __restrict__ vl3w,  const float* __restrict__ vl3b,
                          const float* __restrict__ dw_w,  const float* __restrict__ dw_b,
                          float* __restrict__ wsf, int* __restrict__ wsi)
{
  const int i = blockIdx.x * 256 + threadIdx.x;
  if (i < 111808) {                       // qw8 weight segments
    const float* src; int off;
    if      (i < 4096)   { src = pw1_w; off = 0; }
    else if (i < 37888)  { src = pw2_w; off = 4096; }
    else if (i < 54272)  { src = su1w;  off = 37888; }
    else if (i < 70656)  { src = su2w;  off = 54272; }
    else if (i < 87040)  { src = sdw;   off = 70656; }
    else if (i < 107520) { src = vl1w;  off = 87040; }
    else if (i < 111616) { src = vl2w;  off = 107520; }
    else                 { src = vl3w;  off = 111616; }
    wsf[i] = qw8(src[i - off]);
  } else if (i < 113299) {                // qb32 bias segments
    const int j = i - 111808;
    const float* src; int off;
    if      (j < 64)   { src = pw1_b; off = 0; }
    else if (j < 592)  { src = pw2_b; off = 64; }
    else if (j < 848)  { src = su1b;  off = 592; }
    else if (j < 1104) { src = su2b;  off = 848; }
    else if (j < 1360) { src = sdb;   off = 1104; }
    else if (j < 1424) { src = vl1b;  off = 1360; }
    else if (j < 1488) { src = vl2b;  off = 1424; }
    else               { src = vl3b;  off = 1488; }
    wsf[i] = qb32(src[j - off]);
  } else if (i >= 113300 && i < 113588) { // dwconv weights -> int (scale 65536, int16 range)
    wsi[i] = (int)rintf(fminf(fmaxf(dw_w[i - 113300] * 65536.f, -32768.f), 32767.f));
  } else if (i >= 113588 && i < 113620) { // dwconv bias -> int (scale 128, int16 range)
    wsi[i] = (int)rintf(fminf(fmaxf(dw_b[i - 113588] * 128.f, -32768.f), 32767.f));
  }
}

// ---------------- main fused kernel ----------------
__global__ __launch_bounds__(256, 3)
void nnue_main(const int* __restrict__ line, const float* __restrict__ emb,
               const float* __restrict__ pout_w, const float* __restrict__ pout_b,
               const float* __restrict__ wsf, const int* __restrict__ wsi,
               float* __restrict__ out)
{
  __shared__ unsigned short fbuf[64 * FSTR]; // feature in k-units (value*128), 28928 B
  __shared__ int sle[900];
  __shared__ float sreg[576];                // int K first (via cast), then quantized float
  __shared__ float sfsum[64];
  __shared__ float shh[64];
  __shared__ float sobuf[528];
  __shared__ float spwq[512];
  __shared__ float hstar[576];
  __shared__ float vstar[576];
  __shared__ float squads[256];
  __shared__ float shq[256];
  __shared__ float svq[256];
  __shared__ float sv1[64];
  __shared__ float sv2[64];

  const int tid  = threadIdx.x;
  const int b    = blockIdx.x;
  const int wid  = tid >> 6;
  const int lane = tid & 63;
  const int* le  = line + b * 4 * NPOS;

  // ---------- Phase 1: index preload + deep-pipelined gather ----------
  for (int i = tid; i < 900; i += 256) sle[i] = le[i];
  __syncthreads();

  const int start = (wid * NPOS) >> 2;        // 0,56,112,168
  const int end   = ((wid + 1) * NPOS) >> 2;  // 56,112,168,225
  for (int p0 = start; p0 < end; p0 += 8) {
    float vv[32];
#pragma unroll
    for (int j = 0; j < 8; ++j) {
      int pp = p0 + j; if (pp >= end) pp = end - 1;
#pragma unroll
      for (int d = 0; d < 4; ++d) {
        const int idx = __builtin_amdgcn_readfirstlane(sle[d * NPOS + pp]);
        vv[j * 4 + d] = emb[(size_t)(unsigned)idx * 64u + (unsigned)lane];
      }
    }
#pragma unroll
    for (int j = 0; j < 8; ++j) {
      const int pp = p0 + j;
      if (pp < end) {
        float s = qd32(vv[4 * j]) + qd32(vv[4 * j + 1]) + qd32(vv[4 * j + 2]) + qd32(vv[4 * j + 3]);
        fbuf[lane * FSTR + pp] = (unsigned short)fmaxf(s, 0.f);  // k = relu(f)*128, <=2048
      }
    }
  }
  __syncthreads();

  // ---------- Phase 2: depthwise 3x3 conv, pure integer ----------
  {
    const int cc = tid >> 3;   // channel 0..31
    const int pg = tid & 7;
    int w9[9];
#pragma unroll
    for (int t = 0; t < 9; ++t) w9[t] = wsi[OFF_DWW + cc * 9 + t];
    const int bqi = wsi[OFF_DWB + cc];
    const unsigned short* frow = &fbuf[cc * FSTR];
    int outr[29];
#pragma unroll
    for (int k = 0; k < 29; ++k) {
      const int p = pg + 8 * k;
      int res = 0;
      if (p < NPOS) {
        const int y0 = (p * 2185) >> 15;      // p/15 (magic, exact for p<4681)
        const int x0 = p - y0 * 15;
        const int ym = (y0 > 0), yp = (y0 < 14), xm = (x0 > 0), xp = (x0 < 14);
        int acc = 0;
#pragma unroll
        for (int dy = 0; dy < 3; ++dy) {
          const int vy = (dy == 0) ? ym : ((dy == 2) ? yp : 1);
#pragma unroll
          for (int dx = 0; dx < 3; ++dx) {
            const int vx = (dx == 0) ? xm : ((dx == 2) ? xp : 1);
            int q = p + (dy - 1) * 15 + (dx - 1);
            q = (q < 0) ? 0 : ((q > 224) ? 224 : q);
            int kk = frow[q];                          // x*128 where x=4f -> kk*4 below
            kk = (vy && vx) ? kk : 0;
            acc += (kk * 4 * w9[dy * 3 + dx]) >> 16;   // floor(x*wq*128): (4k*w16)>>16, exact
          }
        }
        res = acc + bqi;                   // conv*128
        res = res < 0 ? 0 : res;           // relu
        res = res > 32767 ? 32767 : res;   // fq(.,128,16) upper clip
      }
      outr[k] = res;
    }
    __syncthreads();  // conv reads complete before overwrite
#pragma unroll
    for (int k = 0; k < 29; ++k) {
      const int p = pg + 8 * k;
      if (p < NPOS) fbuf[cc * FSTR + p] = (unsigned short)outr[k];
    }
  }
  __syncthreads();
  // fbuf = `feature` in k-units exactly (channels>=32 untouched: fq identity)

  // ---------- Phase 3: global + regional sums (integer) ----------
  {
    int* sregKi = (int*)sreg;
    for (int task = tid; task < 576; task += 256) {
      const int r = task >> 6, c = task & 63;
      const int rh = (r * 11) >> 5;          // r/3
      const int rw = r - rh * 3;
      const unsigned short* fr = &fbuf[c * FSTR + rh * 75 + rw * 5];
      int K = 0;
#pragma unroll
      for (int y = 0; y < 5; ++y)
#pragma unroll
        for (int x = 0; x < 5; ++x) K += fr[y * 15 + x];
      sregKi[task] = K;
    }
  }
  __syncthreads();
  if (tid < 64) {
    int* sregKi = (int*)sreg;
    int Ks[9], tot = 0;
#pragma unroll
    for (int r = 0; r < 9; ++r) { Ks[r] = sregKi[r * 64 + tid]; tot += Ks[r]; }
#pragma unroll
    for (int r = 0; r < 9; ++r) sreg[r * 64 + tid] = (float)(Ks[r] >> 5) * 0.0078125f;
    sfsum[tid] = (float)(tot >> 8) * 0.0078125f;
  }
  __syncthreads();

  // ---------- Phase 4: policy MLP ----------
  if (tid < 64) {
    const float4* wr = (const float4*)(wsf + OFF_PW1Q + tid * 64);
    float acc = 0.f;
#pragma unroll
    for (int c4 = 0; c4 < 16; ++c4) {
      float4 w = wr[c4];
      acc += sfsum[c4 * 4 + 0] * w.x;
      acc += sfsum[c4 * 4 + 1] * w.y;
      acc += sfsum[c4 * 4 + 2] * w.z;
      acc += sfsum[c4 * 4 + 3] * w.w;
    }
    shh[tid] = fmaxf(acc + wsf[OFF_PW1B + tid], 0.f);
  }
  __syncthreads();
  for (int j = tid; j < 528; j += 256) {
    const float4* wr = (const float4*)(wsf + OFF_PW2Q + j * 64);
    float acc = 0.f;
#pragma unroll
    for (int c4 = 0; c4 < 16; ++c4) {
      float4 w = wr[c4];
      acc += shh[c4 * 4 + 0] * w.x;
      acc += shh[c4 * 4 + 1] * w.y;
      acc += shh[c4 * 4 + 2] * w.z;
      acc += shh[c4 * 4 + 3] * w.w;
    }
    acc += wsf[OFF_PW2B + j];
    sobuf[j] = acc;
    if (j < 512)   // fq(o,128*128,16,floor)
      spwq[j] = floorf(fminf(fmaxf(acc * 16384.f, -32768.f), 32767.f)) * 6.103515625e-05f;
  }
  __syncthreads();

  // ---------- Phase 5: dynamic pointwise conv + policy out ----------
  if (tid < NPOS) {
    float pinv[32];
#pragma unroll
    for (int c = 0; c < 32; ++c) pinv[c] = (float)fbuf[c * FSTR + tid] * 0.0078125f;
    float acc = 0.f;
#pragma unroll
    for (int i = 0; i < 16; ++i) {
      float s = 0.f;
#pragma unroll
      for (int c = 0; c < 32; ++c) s += pinv[c] * spwq[i * 32 + c];
      s = fmaxf(s + sobuf[512 + i], 0.f);
      acc += s * pout_w[i];
    }
    out[1536 + b * NPOS + tid] = acc + pout_b[0];
  }

  // ---------- Phase 6: 9-region star block ----------
  {
    const int g = tid >> 6;
    const int d = tid & 63;
    int ty, rA, rB, rC, rD;
    if (g == 0)      { ty = 0; rA = 0; rB = 2; rC = 6; rD = 8; }
    else if (g == 1) { ty = 1; rA = 1; rB = 3; rC = 5; rD = 7; }
    else             { ty = 2; rA = 4; rB = 4; rC = 4; rD = 4; }
    const float4* w1r = (const float4*)(wsf + OFF_SU1Q + ty * 4096 + d * 64);
    const float4* w2r = (const float4*)(wsf + OFF_SU2Q + ty * 4096 + d * 64);
    float aA1 = 0, aB1 = 0, aC1 = 0, aD1 = 0, aA2 = 0, aB2 = 0, aC2 = 0, aD2 = 0;
#pragma unroll 4
    for (int c4 = 0; c4 < 16; ++c4) {
      float4 w1 = w1r[c4], w2 = w2r[c4];
      float q1[4] = {w1.x, w1.y, w1.z, w1.w};
      float q2[4] = {w2.x, w2.y, w2.z, w2.w};
#pragma unroll
      for (int u = 0; u < 4; ++u) {
        const int c = c4 * 4 + u;
        float xA = sreg[rA * 64 + c], xB = sreg[rB * 64 + c];
        float xC = sreg[rC * 64 + c], xD = sreg[rD * 64 + c];
        aA1 += xA * q1[u]; aB1 += xB * q1[u]; aC1 += xC * q1[u]; aD1 += xD * q1[u];
        aA2 += xA * q2[u]; aB2 += xB * q2[u]; aC2 += xC * q2[u]; aD2 += xD * q2[u];
      }
    }
    const float bb1 = wsf[OFF_SU1B + ty * 64 + d];
    const float bb2 = wsf[OFF_SU2B + ty * 64 + d];
    hstar[rA * 64 + d] = fmaxf(aA1 + bb1, 0.f) * (aA2 + bb2);
    hstar[rB * 64 + d] = fmaxf(aB1 + bb1, 0.f) * (aB2 + bb2);
    hstar[rC * 64 + d] = fmaxf(aC1 + bb1, 0.f) * (aC2 + bb2);
    hstar[rD * 64 + d] = fmaxf(aD1 + bb1, 0.f) * (aD2 + bb2);
    __syncthreads();
    const float4* wdr = (const float4*)(wsf + OFF_SDQ + ty * 4096 + d * 64);
    float dA = 0, dB = 0, dC = 0, dD = 0;
#pragma unroll 4
    for (int c4 = 0; c4 < 16; ++c4) {
      float4 w = wdr[c4];
      float q[4] = {w.x, w.y, w.z, w.w};
#pragma unroll
      for (int u = 0; u < 4; ++u) {
        const int c = c4 * 4 + u;
        dA += hstar[rA * 64 + c] * q[u]; dB += hstar[rB * 64 + c] * q[u];
        dC += hstar[rC * 64 + c] * q[u]; dD += hstar[rD * 64 + c] * q[u];
      }
    }
    const float bd = wsf[OFF_SDB + ty * 64 + d];
    vstar[rA * 64 + d] = dA + bd;
    vstar[rB * 64 + d] = dB + bd;
    vstar[rC * 64 + d] = dC + bd;
    vstar[rD * 64 + d] = dD + bd;
  }
  __syncthreads();

  // ---------- Phase 7: quad averaging ----------
  {
    const int g = tid >> 6, d = tid & 63;
    int r0, r1, r2v, r3v;
    if (g == 0)      { r0 = 0; r1 = 1; r2v = 3; r3v = 4; }
    else if (g == 1) { r0 = 1; r1 = 2; r2v = 4; r3v = 5; }
    else if (g == 2) { r0 = 3; r1 = 4; r2v = 6; r3v = 7; }
    else             { r0 = 4; r1 = 5; r2v = 7; r3v = 8; }
    float a  = fq8f(vstar[r0 * 64 + d]);
    float bb = fq8f(vstar[r1 * 64 + d]);
    float cc = fq8f(vstar[r2v * 64 + d]);
    float dd = fq8f(vstar[r3v * 64 + d]);
    float ab = fq8f((a + bb + 0.0078125f) * 0.5f);
    float cd = fq8f((cc + dd + 0.0078125f) * 0.5f);
    squads[g * 64 + d] = fq8f((ab + cd + 0.0078125f) * 0.5f);
  }
  __syncthreads();

  // ---------- Phase 8: quad star block (type 3) ----------
  {
    const int g = tid >> 6, d = tid & 63;
    const float4* w1r = (const float4*)(wsf + OFF_SU1Q + 3 * 4096 + d * 64);
    const float4* w2r = (const float4*)(wsf + OFF_SU2Q + 3 * 4096 + d * 64);
    float a1 = 0.f, a2 = 0.f;
#pragma unroll 4
    for (int c4 = 0; c4 < 16; ++c4) {
      float4 w1 = w1r[c4], w2 = w2r[c4];
      float xq0 = squads[g * 64 + c4 * 4 + 0], xq1 = squads[g * 64 + c4 * 4 + 1];
      float xq2 = squads[g * 64 + c4 * 4 + 2], xq3 = squads[g * 64 + c4 * 4 + 3];
      a1 += xq0 * w1.x + xq1 * w1.y + xq2 * w1.z + xq3 * w1.w;
      a2 += xq0 * w2.x + xq1 * w2.y + xq2 * w2.z + xq3 * w2.w;
    }
    shq[g * 64 + d] = fmaxf(a1 + wsf[OFF_SU1B + 192 + d], 0.f) * (a2 + wsf[OFF_SU2B + 192 + d]);
    __syncthreads();
    const float4* wdr = (const float4*)(wsf + OFF_SDQ + 3 * 4096 + d * 64);
    float ad = 0.f;
#pragma unroll 4
    for (int c4 = 0; c4 < 16; ++c4) {
      float4 w = wdr[c4];
      ad += shq[g * 64 + c4 * 4 + 0] * w.x + shq[g * 64 + c4 * 4 + 1] * w.y
          + shq[g * 64 + c4 * 4 + 2] * w.z + shq[g * 64 + c4 * 4 + 3] * w.w;
    }
    svq[g * 64 + d] = ad + wsf[OFF_SDB + 192 + d];
  }
  __syncthreads();

  // ---------- Phase 9: value MLP [320]->64->64->3 ----------
  if (tid < 64) {
    const float4* wr = (const float4*)(wsf + OFF_VL1Q + tid * 320);
    float acc = 0.f;
#pragma unroll 4
    for (int k4 = 0; k4 < 16; ++k4) {
      float4 w = wr[k4];
      acc += sfsum[k4 * 4 + 0] * w.x;
      acc += sfsum[k4 * 4 + 1] * w.y;
      acc += sfsum[k4 * 4 + 2] * w.z;
      acc += sfsum[k4 * 4 + 3] * w.w;
    }
#pragma unroll 4
    for (int k4 = 16; k4 < 80; ++k4) {
      float4 w = wr[k4];
      const int base = k4 * 4 - 64;
      acc += svq[base + 0] * w.x;
      acc += svq[base + 1] * w.y;
      acc += svq[base + 2] * w.z;
      acc += svq[base + 3] * w.w;
    }
    sv1[tid] = fmaxf(acc + wsf[OFF_VL1B + tid], 0.f);
  }
  __syncthreads();
  if (tid < 64) {
    const float4* wr = (const float4*)(wsf + OFF_VL2Q + tid * 64);
    float acc = 0.f;
#pragma unroll 4
    for (int k4 = 0; k4 < 16; ++k4) {
      float4 w = wr[k4];
      acc += sv1[k4 * 4 + 0] * w.x;
      acc += sv1[k4 * 4 + 1] * w.y;
      acc += sv1[k4 * 4 + 2] * w.z;
      acc += sv1[k4 * 4 + 3] * w.w;
    }
    sv2[tid] = fmaxf(acc + wsf[OFF_VL2B + tid], 0.f);
  }
  __syncthreads();
  if (tid < 3) {
    const float* wr = wsf + OFF_VL3Q + tid * 64;
    float acc = 0.f;
#pragma unroll
    for (int k = 0; k < 64; ++k) acc += sv2[k] * wr[k];
    out[b * 3 + tid] = acc + wsf[OFF_VL3B + tid];
  }
}

extern "C" void kernel_launch(void* const* d_in, const int* in_sizes, int n_in,
                              void* d_out, int out_size, void* d_ws, size_t ws_size,
                              hipStream_t stream) {
  (void)in_sizes; (void)n_in; (void)out_size; (void)ws_size;
  float* wsf = (float*)d_ws;
  int*   wsi = (int*)d_ws;
  nnue_prep<<<(WS_TOTAL + 255) / 256, 256, 0, stream>>>(
      (const float*)d_in[4],  (const float*)d_in[5],
      (const float*)d_in[6],  (const float*)d_in[7],
      (const float*)d_in[10], (const float*)d_in[11],
      (const float*)d_in[12], (const float*)d_in[13],
      (const float*)d_in[14], (const float*)d_in[15],
      (const float*)d_in[16], (const float*)d_in[17],
      (const float*)d_in[18], (const float*)d_in[19],
      (const float*)d_in[20], (const float*)d_in[21],
      (const float*)d_in[2],  (const float*)d_in[3],
      wsf, wsi);
  nnue_main<<<512, 256, 0, stream>>>(
      (const int*)d_in[0], (const float*)d_in[1],
      (const float*)d_in[8], (const float*)d_in[9],
      wsf, wsi, (float*)d_out);
}

// Round 4
// 253.021 us; speedup vs baseline: 1.1270x; 1.0281x over previous
//
#include <hip/hip_runtime.h>

#define NPOS 225
#define FSTR 226   // ushort stride: dword stride 113 (odd, coprime 32) -> conflict-free

// ---- workspace layout (float words unless noted) ----
#define OFF_PW1Q 0
#define OFF_PW2Q 4096
#define OFF_SU1Q 37888
#define OFF_SU2Q 54272
#define OFF_SDQ  70656
#define OFF_VL1Q 87040
#define OFF_VL2Q 107520
#define OFF_VL3Q 111616
#define OFF_PW1B 111808
#define OFF_PW2B 111872
#define OFF_SU1B 112400
#define OFF_SU2B 112656
#define OFF_SDB  112912
#define OFF_VL1B 113168
#define OFF_VL2B 113232
#define OFF_VL3B 113296
#define OFF_DWW  113300   // 288 ints (dwconv weights * 65536, int16 range)
#define OFF_DWB  113588   // 32 ints  (dwconv bias * 128, int16 range)
#define WS_TOTAL 113620

__device__ __forceinline__ float qw8(float w) {
  return rintf(fminf(fmaxf(w * 128.f, -128.f), 127.f)) * 0.0078125f;
}
__device__ __forceinline__ float qb32(float b) {
  return rintf(b * 16384.f) * 6.103515625e-05f;
}
__device__ __forceinline__ float fq8f(float v) {
  return floorf(fminf(fmaxf(v * 128.f, -128.f), 127.f)) * 0.0078125f;
}
__device__ __forceinline__ float qd32(float v) {   // rint(clip(v,+-16)*32): integer-valued
  return rintf(fminf(fmaxf(v, -16.f), 16.f) * 32.f);
}

// ---------------- prep: quantize all static weights once ----------------
__global__ void nnue_prep(const float* __restrict__ pw1_w, const float* __restrict__ pw1_b,
                          const float* __restrict__ pw2_w, const float* __restrict__ pw2_b,
                          const float* __restrict__ su1w,  const float* __restrict__ su1b,
                          const float* __restrict__ su2w,  const float* __restrict__ su2b,
                          const float* __restrict__ sdw,   const float* __restrict__ sdb,
                          const float* __restrict__ vl1w,  const float* __restrict__ vl1b,
                          const float* __restrict__ vl2w,  const float* __restrict__ vl2b,
                          const float* __restrict__ vl3w,  const float* __restrict__ vl3b,
                          const float* __restrict__ dw_w,  const float* __restrict__ dw_b,
                          float* __restrict__ wsf, int* __restrict__ wsi)
{
  const int i = blockIdx.x * 256 + threadIdx.x;
  if (i < 111808) {
    const float* src; int off;
    if      (i < 4096)   { src = pw1_w; off = 0; }
    else if (i < 37888)  { src = pw2_w; off = 4096; }
    else if (i < 54272)  { src = su1w;  off = 37888; }
    else if (i < 70656)  { src = su2w;  off = 54272; }
    else if (i < 87040)  { src = sdw;   off = 70656; }
    else if (i < 107520) { src = vl1w;  off = 87040; }
    else if (i < 111616) { src = vl2w;  off = 107520; }
    else                 { src = vl3w;  off = 111616; }
    wsf[i] = qw8(src[i - off]);
  } else if (i < 113299) {
    const int j = i - 111808;
    const float* src; int off;
    if      (j < 64)   { src = pw1_b; off = 0; }
    else if (j < 592)  { src = pw2_b; off = 64; }
    else if (j < 848)  { src = su1b;  off = 592; }
    else if (j < 1104) { src = su2b;  off = 848; }
    else if (j < 1360) { src = sdb;   off = 1104; }
    else if (j < 1424) { src = vl1b;  off = 1360; }
    else if (j < 1488) { src = vl2b;  off = 1424; }
    else               { src = vl3b;  off = 1488; }
    wsf[i] = qb32(src[j - off]);
  } else if (i >= 113300 && i < 113588) {
    wsi[i] = (int)rintf(fminf(fmaxf(dw_w[i - 113300] * 65536.f, -32768.f), 32767.f));
  } else if (i >= 113588 && i < 113620) {
    wsi[i] = (int)rintf(fminf(fmaxf(dw_b[i - 113588] * 128.f, -32768.f), 32767.f));
  }
}

// ---------------- main fused kernel: 512 threads (8 waves) ----------------
__global__ __launch_bounds__(512, 4)
void nnue_main(const int* __restrict__ line, const float* __restrict__ emb,
               const float* __restrict__ pout_w, const float* __restrict__ pout_b,
               const float* __restrict__ wsf, const int* __restrict__ wsi,
               float* __restrict__ out)
{
  __shared__ unsigned short fbuf[64 * FSTR]; // feature in k-units (value*128), 28928 B
  __shared__ float sreg[576];
  __shared__ float sfsum[64];
  __shared__ float shh[64];
  __shared__ float sobuf[528];
  __shared__ float spwq[512];
  __shared__ float hstar[576];
  __shared__ float vstar[576];
  __shared__ float squads[256];
  __shared__ float shq[256];
  __shared__ float svq[256];
  __shared__ float sv1[64];
  __shared__ float sv2[64];

  const int tid  = threadIdx.x;
  const int b    = blockIdx.x;
  const int wid  = __builtin_amdgcn_readfirstlane(tid >> 6);  // uniform -> scalar idx loads
  const int lane = tid & 63;
  const int* le  = line + b * 4 * NPOS;

  // ---------- Phase 1: gather (batched uniform index loads + saddr row gathers) ----------
  {
    const int s = (wid * NPOS) >> 3;         // 28 or 29 positions per wave
    const int e = ((wid + 1) * NPOS) >> 3;
    for (int p0 = s; p0 < e; p0 += 8) {
      int idx[32];
#pragma unroll
      for (int j = 0; j < 8; ++j) {
        int pp = p0 + j; pp = (pp < e) ? pp : (e - 1);
#pragma unroll
        for (int d = 0; d < 4; ++d) idx[j * 4 + d] = le[d * NPOS + pp];
      }
      float vv[32];
#pragma unroll
      for (int t = 0; t < 32; ++t)
        vv[t] = emb[(unsigned)(idx[t] * 64 + lane)];
#pragma unroll
      for (int j = 0; j < 8; ++j) {
        int pp = p0 + j; pp = (pp < e) ? pp : (e - 1);
        float sm = qd32(vv[4 * j]) + qd32(vv[4 * j + 1]) + qd32(vv[4 * j + 2]) + qd32(vv[4 * j + 3]);
        fbuf[lane * FSTR + pp] = (unsigned short)fmaxf(sm, 0.f);  // k = relu(f)*128 <= 2048
      }
    }
  }
  __syncthreads();

  // ---------- Phase 2: depthwise 3x3 conv, pure integer ----------
  {
    const int cc = tid >> 4;   // channel 0..31 (16 threads each, within one wave)
    const int pg = tid & 15;
    int w9[9];
#pragma unroll
    for (int t = 0; t < 9; ++t) w9[t] = wsi[OFF_DWW + cc * 9 + t];
    const int bqi = wsi[OFF_DWB + cc];
    const unsigned short* frow = &fbuf[cc * FSTR];
    int outr[15];
#pragma unroll
    for (int k = 0; k < 15; ++k) {
      const int p = pg + 16 * k;
      int res = 0;
      if (p < NPOS) {
        const int y0 = (p * 2185) >> 15;      // p/15 exact
        const int x0 = p - y0 * 15;
        const int ym = (y0 > 0), yp = (y0 < 14), xm = (x0 > 0), xp = (x0 < 14);
        int acc = 0;
#pragma unroll
        for (int dy = 0; dy < 3; ++dy) {
          const int vy = (dy == 0) ? ym : ((dy == 2) ? yp : 1);
#pragma unroll
          for (int dx = 0; dx < 3; ++dx) {
            const int vx = (dx == 0) ? xm : ((dx == 2) ? xp : 1);
            int q = p + (dy - 1) * 15 + (dx - 1);
            q = (q < 0) ? 0 : ((q > 224) ? 224 : q);
            int kk = frow[q];
            kk = (vy && vx) ? kk : 0;
            acc += (kk * 4 * w9[dy * 3 + dx]) >> 16;   // floor(x*wq*128), exact
          }
        }
        res = acc + bqi;
        res = res < 0 ? 0 : res;
        res = res > 32767 ? 32767 : res;
      }
      outr[k] = res;
    }
    __syncthreads();
#pragma unroll
    for (int k = 0; k < 15; ++k) {
      const int p = pg + 16 * k;
      if (p < NPOS) fbuf[cc * FSTR + p] = (unsigned short)outr[k];
    }
  }
  __syncthreads();

  // ---------- Phase 3: global + regional sums (integer) ----------
  {
    int* sregKi = (int*)sreg;
    for (int task = tid; task < 576; task += 512) {
      const int r = task >> 6, c = task & 63;
      const int rh = (r * 11) >> 5;
      const int rw = r - rh * 3;
      const unsigned short* fr = &fbuf[c * FSTR + rh * 75 + rw * 5];
      int K = 0;
#pragma unroll
      for (int y = 0; y < 5; ++y)
#pragma unroll
        for (int x = 0; x < 5; ++x) K += fr[y * 15 + x];
      sregKi[task] = K;
    }
  }
  __syncthreads();
  if (tid < 64) {
    int* sregKi = (int*)sreg;
    int Ks[9], tot = 0;
#pragma unroll
    for (int r = 0; r < 9; ++r) { Ks[r] = sregKi[r * 64 + tid]; tot += Ks[r]; }
#pragma unroll
    for (int r = 0; r < 9; ++r) sreg[r * 64 + tid] = (float)(Ks[r] >> 5) * 0.0078125f;
    sfsum[tid] = (float)(tot >> 8) * 0.0078125f;
  }
  __syncthreads();   // == B0: policy path (waves 0-3) || value path (waves 4-7)

  // ---------- Seg1: policy shh | value star-up ----------
  if (tid < 64) {
    const float4* wr = (const float4*)(wsf + OFF_PW1Q + tid * 64);
    float acc = 0.f;
#pragma unroll
    for (int c4 = 0; c4 < 16; ++c4) {
      float4 w = wr[c4];
      acc += sfsum[c4 * 4 + 0] * w.x + sfsum[c4 * 4 + 1] * w.y
           + sfsum[c4 * 4 + 2] * w.z + sfsum[c4 * 4 + 3] * w.w;
    }
    shh[tid] = fmaxf(acc + wsf[OFF_PW1B + tid], 0.f);
  } else if (tid >= 256) {
    const int g = (tid >> 6) - 4;
    const int d = tid & 63;
    int ty, rA, rB, rC, rD;
    if (g == 0)      { ty = 0; rA = 0; rB = 2; rC = 6; rD = 8; }
    else if (g == 1) { ty = 1; rA = 1; rB = 3; rC = 5; rD = 7; }
    else if (g == 2) { ty = 2; rA = 4; rB = 4; rC = 4; rD = 4; }
    else             { ty = 3; rA = 4; rB = 4; rC = 4; rD = 4; }
    if (g < 3) {
      const float4* w1r = (const float4*)(wsf + OFF_SU1Q + ty * 4096 + d * 64);
      const float4* w2r = (const float4*)(wsf + OFF_SU2Q + ty * 4096 + d * 64);
      float aA1 = 0, aB1 = 0, aC1 = 0, aD1 = 0, aA2 = 0, aB2 = 0, aC2 = 0, aD2 = 0;
#pragma unroll 4
      for (int c4 = 0; c4 < 16; ++c4) {
        float4 w1 = w1r[c4], w2 = w2r[c4];
        float q1[4] = {w1.x, w1.y, w1.z, w1.w};
        float q2[4] = {w2.x, w2.y, w2.z, w2.w};
#pragma unroll
        for (int u = 0; u < 4; ++u) {
          const int c = c4 * 4 + u;
          float xA = sreg[rA * 64 + c], xB = sreg[rB * 64 + c];
          float xC = sreg[rC * 64 + c], xD = sreg[rD * 64 + c];
          aA1 += xA * q1[u]; aB1 += xB * q1[u]; aC1 += xC * q1[u]; aD1 += xD * q1[u];
          aA2 += xA * q2[u]; aB2 += xB * q2[u]; aC2 += xC * q2[u]; aD2 += xD * q2[u];
        }
      }
      const float bb1 = wsf[OFF_SU1B + ty * 64 + d];
      const float bb2 = wsf[OFF_SU2B + ty * 64 + d];
      hstar[rA * 64 + d] = fmaxf(aA1 + bb1, 0.f) * (aA2 + bb2);
      hstar[rB * 64 + d] = fmaxf(aB1 + bb1, 0.f) * (aB2 + bb2);
      hstar[rC * 64 + d] = fmaxf(aC1 + bb1, 0.f) * (aC2 + bb2);
      hstar[rD * 64 + d] = fmaxf(aD1 + bb1, 0.f) * (aD2 + bb2);
    }
  }
  __syncthreads();   // == B1

  // ---------- Seg2: policy o/spwq | value star-down ----------
  if (tid < 256) {
    for (int j = tid; j < 528; j += 256) {
      const float4* wr = (const float4*)(wsf + OFF_PW2Q + j * 64);
      float acc = 0.f;
#pragma unroll
      for (int c4 = 0; c4 < 16; ++c4) {
        float4 w = wr[c4];
        acc += shh[c4 * 4 + 0] * w.x + shh[c4 * 4 + 1] * w.y
             + shh[c4 * 4 + 2] * w.z + shh[c4 * 4 + 3] * w.w;
      }
      acc += wsf[OFF_PW2B + j];
      sobuf[j] = acc;
      if (j < 512)
        spwq[j] = floorf(fminf(fmaxf(acc * 16384.f, -32768.f), 32767.f)) * 6.103515625e-05f;
    }
  } else {
    const int g = (tid >> 6) - 4;
    const int d = tid & 63;
    int ty, rA, rB, rC, rD;
    if (g == 0)      { ty = 0; rA = 0; rB = 2; rC = 6; rD = 8; }
    else if (g == 1) { ty = 1; rA = 1; rB = 3; rC = 5; rD = 7; }
    else             { ty = 2; rA = 4; rB = 4; rC = 4; rD = 4; }
    if (g < 3) {
      const float4* wdr = (const float4*)(wsf + OFF_SDQ + ty * 4096 + d * 64);
      float dA = 0, dB = 0, dC = 0, dD = 0;
#pragma unroll 4
      for (int c4 = 0; c4 < 16; ++c4) {
        float4 w = wdr[c4];
        float q[4] = {w.x, w.y, w.z, w.w};
#pragma unroll
        for (int u = 0; u < 4; ++u) {
          const int c = c4 * 4 + u;
          dA += hstar[rA * 64 + c] * q[u]; dB += hstar[rB * 64 + c] * q[u];
          dC += hstar[rC * 64 + c] * q[u]; dD += hstar[rD * 64 + c] * q[u];
        }
      }
      const float bd = wsf[OFF_SDB + ty * 64 + d];
      vstar[rA * 64 + d] = dA + bd;
      vstar[rB * 64 + d] = dB + bd;
      vstar[rC * 64 + d] = dC + bd;
      vstar[rD * 64 + d] = dD + bd;
    }
  }
  __syncthreads();   // == B2

  // ---------- Seg3: policy pixel conv + out | value quads ----------
  if (tid < NPOS) {
    float pinv[32];
#pragma unroll
    for (int c = 0; c < 32; ++c) pinv[c] = (float)fbuf[c * FSTR + tid] * 0.0078125f;
    float acc = 0.f;
#pragma unroll
    for (int i = 0; i < 16; ++i) {
      float s = 0.f;
#pragma unroll
      for (int c = 0; c < 32; ++c) s += pinv[c] * spwq[i * 32 + c];
      s = fmaxf(s + sobuf[512 + i], 0.f);
      acc += s * pout_w[i];
    }
    out[1536 + b * NPOS + tid] = acc + pout_b[0];
  } else if (tid >= 256) {
    const int g = (tid >> 6) - 4;
    const int d = tid & 63;
    int r0, r1, r2v, r3v;
    if (g == 0)      { r0 = 0; r1 = 1; r2v = 3; r3v = 4; }
    else if (g == 1) { r0 = 1; r1 = 2; r2v = 4; r3v = 5; }
    else if (g == 2) { r0 = 3; r1 = 4; r2v = 6; r3v = 7; }
    else             { r0 = 4; r1 = 5; r2v = 7; r3v = 8; }
    float a  = fq8f(vstar[r0 * 64 + d]);
    float bb = fq8f(vstar[r1 * 64 + d]);
    float cc = fq8f(vstar[r2v * 64 + d]);
    float dd = fq8f(vstar[r3v * 64 + d]);
    float ab = fq8f((a + bb + 0.0078125f) * 0.5f);
    float cd = fq8f((cc + dd + 0.0078125f) * 0.5f);
    squads[g * 64 + d] = fq8f((ab + cd + 0.0078125f) * 0.5f);
  }
  __syncthreads();   // == B3

  // ---------- Seg4: quad star up ----------
  if (tid >= 256) {
    const int g = (tid >> 6) - 4;
    const int d = tid & 63;
    const float4* w1r = (const float4*)(wsf + OFF_SU1Q + 3 * 4096 + d * 64);
    const float4* w2r = (const float4*)(wsf + OFF_SU2Q + 3 * 4096 + d * 64);
    float a1 = 0.f, a2 = 0.f;
#pragma unroll 4
    for (int c4 = 0; c4 < 16; ++c4) {
      float4 w1 = w1r[c4], w2 = w2r[c4];
      float xq0 = squads[g * 64 + c4 * 4 + 0], xq1 = squads[g * 64 + c4 * 4 + 1];
      float xq2 = squads[g * 64 + c4 * 4 + 2], xq3 = squads[g * 64 + c4 * 4 + 3];
      a1 += xq0 * w1.x + xq1 * w1.y + xq2 * w1.z + xq3 * w1.w;
      a2 += xq0 * w2.x + xq1 * w2.y + xq2 * w2.z + xq3 * w2.w;
    }
    shq[g * 64 + d] = fmaxf(a1 + wsf[OFF_SU1B + 192 + d], 0.f) * (a2 + wsf[OFF_SU2B + 192 + d]);
  }
  __syncthreads();   // == B4

  // ---------- Seg5: quad star down ----------
  if (tid >= 256) {
    const int g = (tid >> 6) - 4;
    const int d = tid & 63;
    const float4* wdr = (const float4*)(wsf + OFF_SDQ + 3 * 4096 + d * 64);
    float ad = 0.f;
#pragma unroll 4
    for (int c4 = 0; c4 < 16; ++c4) {
      float4 w = wdr[c4];
      ad += shq[g * 64 + c4 * 4 + 0] * w.x + shq[g * 64 + c4 * 4 + 1] * w.y
          + shq[g * 64 + c4 * 4 + 2] * w.z + shq[g * 64 + c4 * 4 + 3] * w.w;
    }
    svq[g * 64 + d] = ad + wsf[OFF_SDB + 192 + d];
  }
  __syncthreads();   // == B5

  // ---------- Seg6-8: value MLP [320]->64->64->3 ----------
  if (tid < 64) {
    const float4* wr = (const float4*)(wsf + OFF_VL1Q + tid * 320);
    float acc = 0.f;
#pragma unroll 4
    for (int k4 = 0; k4 < 16; ++k4) {
      float4 w = wr[k4];
      acc += sfsum[k4 * 4 + 0] * w.x + sfsum[k4 * 4 + 1] * w.y
           + sfsum[k4 * 4 + 2] * w.z + sfsum[k4 * 4 + 3] * w.w;
    }
#pragma unroll 4
    for (int k4 = 16; k4 < 80; ++k4) {
      float4 w = wr[k4];
      const int base = k4 * 4 - 64;
      acc += svq[base + 0] * w.x + svq[base + 1] * w.y
           + svq[base + 2] * w.z + svq[base + 3] * w.w;
    }
    sv1[tid] = fmaxf(acc + wsf[OFF_VL1B + tid], 0.f);
  }
  __syncthreads();
  if (tid < 64) {
    const float4* wr = (const float4*)(wsf + OFF_VL2Q + tid * 64);
    float acc = 0.f;
#pragma unroll 4
    for (int k4 = 0; k4 < 16; ++k4) {
      float4 w = wr[k4];
      acc += sv1[k4 * 4 + 0] * w.x + sv1[k4 * 4 + 1] * w.y
           + sv1[k4 * 4 + 2] * w.z + sv1[k4 * 4 + 3] * w.w;
    }
    sv2[tid] = fmaxf(acc + wsf[OFF_VL2B + tid], 0.f);
  }
  __syncthreads();
  if (tid < 3) {
    const float* wr = wsf + OFF_VL3Q + tid * 64;
    float acc = 0.f;
#pragma unroll
    for (int k = 0; k < 64; ++k) acc += sv2[k] * wr[k];
    out[b * 3 + tid] = acc + wsf[OFF_VL3B + tid];
  }
}

extern "C" void kernel_launch(void* const* d_in, const int* in_sizes, int n_in,
                              void* d_out, int out_size, void* d_ws, size_t ws_size,
                              hipStream_t stream) {
  (void)in_sizes; (void)n_in; (void)out_size; (void)ws_size;
  float* wsf = (float*)d_ws;
  int*   wsi = (int*)d_ws;
  nnue_prep<<<(WS_TOTAL + 255) / 256, 256, 0, stream>>>(
      (const float*)d_in[4],  (const float*)d_in[5],
      (const float*)d_in[6],  (const float*)d_in[7],
      (const float*)d_in[10], (const float*)d_in[11],
      (const float*)d_in[12], (const float*)d_in[13],
      (const float*)d_in[14], (const float*)d_in[15],
      (const float*)d_in[16], (const float*)d_in[17],
      (const float*)d_in[18], (const float*)d_in[19],
      (const float*)d_in[20], (const float*)d_in[21],
      (const float*)d_in[2],  (const float*)d_in[3],
      wsf, wsi);
  nnue_main<<<512, 512, 0, stream>>>(
      (const int*)d_in[0], (const float*)d_in[1],
      (const float*)d_in[8], (const float*)d_in[9],
      wsf, wsi, (float*)d_out);
}

// Round 5
// 250.229 us; speedup vs baseline: 1.1396x; 1.0112x over previous
//
#include <hip/hip_runtime.h>

#define NPOS 225
#define FSTR 226   // ushort stride: dword stride 113 (odd, coprime 32) -> conflict-free

// ---- workspace layout (float words unless noted) ----
#define OFF_PW1Q 0
#define OFF_PW2Q 4096
#define OFF_SU1Q 37888
#define OFF_SU2Q 54272
#define OFF_SDQ  70656
#define OFF_VL1Q 87040
#define OFF_VL2Q 107520
#define OFF_VL3Q 111616
#define OFF_PW1B 111808
#define OFF_PW2B 111872
#define OFF_SU1B 112400
#define OFF_SU2B 112656
#define OFF_SDB  112912
#define OFF_VL1B 113168
#define OFF_VL2B 113232
#define OFF_VL3B 113296
#define OFF_DWW  113300   // 288 ints (dwconv weights * 65536, int16 range)
#define OFF_DWB  113588   // 32 ints  (dwconv bias * 128, int16 range)
#define WS_TOTAL 113620

__device__ __forceinline__ float qw8(float w) {
  return rintf(fminf(fmaxf(w * 128.f, -128.f), 127.f)) * 0.0078125f;
}
__device__ __forceinline__ float qb32(float b) {
  return rintf(b * 16384.f) * 6.103515625e-05f;
}
__device__ __forceinline__ float fq8f(float v) {
  return floorf(fminf(fmaxf(v * 128.f, -128.f), 127.f)) * 0.0078125f;
}
__device__ __forceinline__ float qd32(float v) {   // rint(clip(v,+-16)*32): integer-valued
  return rintf(fminf(fmaxf(v, -16.f), 16.f) * 32.f);
}

// ---------------- prep: quantize all static weights once ----------------
__global__ void nnue_prep(const float* __restrict__ pw1_w, const float* __restrict__ pw1_b,
                          const float* __restrict__ pw2_w, const float* __restrict__ pw2_b,
                          const float* __restrict__ su1w,  const float* __restrict__ su1b,
                          const float* __restrict__ su2w,  const float* __restrict__ su2b,
                          const float* __restrict__ sdw,   const float* __restrict__ sdb,
                          const float* __restrict__ vl1w,  const float* __restrict__ vl1b,
                          const float* __restrict__ vl2w,  const float* __restrict__ vl2b,
                          const float* __restrict__ vl3w,  const float* __restrict__ vl3b,
                          const float* __restrict__ dw_w,  const float* __restrict__ dw_b,
                          float* __restrict__ wsf, int* __restrict__ wsi)
{
  const int i = blockIdx.x * 256 + threadIdx.x;
  if (i < 111808) {
    const float* src; int off;
    if      (i < 4096)   { src = pw1_w; off = 0; }
    else if (i < 37888)  { src = pw2_w; off = 4096; }
    else if (i < 54272)  { src = su1w;  off = 37888; }
    else if (i < 70656)  { src = su2w;  off = 54272; }
    else if (i < 87040)  { src = sdw;   off = 70656; }
    else if (i < 107520) { src = vl1w;  off = 87040; }
    else if (i < 111616) { src = vl2w;  off = 107520; }
    else                 { src = vl3w;  off = 111616; }
    wsf[i] = qw8(src[i - off]);
  } else if (i < 113299) {
    const int j = i - 111808;
    const float* src; int off;
    if      (j < 64)   { src = pw1_b; off = 0; }
    else if (j < 592)  { src = pw2_b; off = 64; }
    else if (j < 848)  { src = su1b;  off = 592; }
    else if (j < 1104) { src = su2b;  off = 848; }
    else if (j < 1360) { src = sdb;   off = 1104; }
    else if (j < 1424) { src = vl1b;  off = 1360; }
    else if (j < 1488) { src = vl2b;  off = 1424; }
    else               { src = vl3b;  off = 1488; }
    wsf[i] = qb32(src[j - off]);
  } else if (i >= 113300 && i < 113588) {
    wsi[i] = (int)rintf(fminf(fmaxf(dw_w[i - 113300] * 65536.f, -32768.f), 32767.f));
  } else if (i >= 113588 && i < 113620) {
    wsi[i] = (int)rintf(fminf(fmaxf(dw_b[i - 113588] * 128.f, -32768.f), 32767.f));
  }
}

// ---------------- main fused kernel: 512 threads (8 waves) ----------------
__global__ __launch_bounds__(512, 4)
void nnue_main(const int* __restrict__ line, const float* __restrict__ emb,
               const float* __restrict__ pout_w, const float* __restrict__ pout_b,
               const float* __restrict__ wsf, const int* __restrict__ wsi,
               float* __restrict__ out)
{
  __shared__ unsigned short fbuf[64 * FSTR];  // f (all 64 ch), k-units, 28928 B
  __shared__ unsigned short fbuf2[32 * FSTR]; // dwconv output ch 0..31, 14464 B
  __shared__ int sle[900];
  __shared__ float sreg[576];
  __shared__ float sfsum[64];
  __shared__ float shh[64];
  __shared__ float sobuf[528];
  __shared__ float spwq[512];
  __shared__ float hstar[576];
  __shared__ float vstar[576];
  __shared__ float squads[256];
  __shared__ float shq[256];
  __shared__ float svq[256];
  __shared__ float sv1[64];
  __shared__ float sv2[64];

  const int tid  = threadIdx.x;
  const int b    = blockIdx.x;
  const int wid  = __builtin_amdgcn_readfirstlane(tid >> 6);
  const int lane = tid & 63;
  const int* le  = line + b * 4 * NPOS;

  // ---------- Phase 0: stage indices in LDS (one coalesced burst) ----------
  for (int i = tid; i < 900; i += 512) sle[i] = le[i];
  __syncthreads();

  // ---------- Phase 1: gather; indices in SGPRs, only dest VGPRs live ----------
  {
    const int s = (wid * NPOS) >> 3;         // 28 or 29 positions per wave
    const int e = ((wid + 1) * NPOS) >> 3;
    for (int p0 = s; p0 < e; p0 += 8) {
      int sidx[32];                          // SGPRs via readfirstlane
#pragma unroll
      for (int j = 0; j < 8; ++j) {
        int pp = p0 + j; pp = (pp < e) ? pp : (e - 1);
#pragma unroll
        for (int d = 0; d < 4; ++d)
          sidx[j * 4 + d] = __builtin_amdgcn_readfirstlane(sle[d * NPOS + pp]);
      }
      float vv[32];
#pragma unroll
      for (int t = 0; t < 32; ++t)
        vv[t] = emb[(unsigned)(sidx[t] * 64 + lane)];
#pragma unroll
      for (int j = 0; j < 8; ++j) {
        int pp = p0 + j; pp = (pp < e) ? pp : (e - 1);
        float sm = qd32(vv[4 * j]) + qd32(vv[4 * j + 1]) + qd32(vv[4 * j + 2]) + qd32(vv[4 * j + 3]);
        fbuf[lane * FSTR + pp] = (unsigned short)fmaxf(sm, 0.f);  // k = relu(f)*128 <= 2048
      }
    }
  }
  __syncthreads();

  // ---------- Phase 2: depthwise 3x3 conv (integer) -> fbuf2 (no reg array) ----------
  {
    const int cc = tid >> 4;   // channel 0..31
    const int pg = tid & 15;
    int w9[9];
#pragma unroll
    for (int t = 0; t < 9; ++t) w9[t] = wsi[OFF_DWW + cc * 9 + t];
    const int bqi = wsi[OFF_DWB + cc];
    const unsigned short* frow = &fbuf[cc * FSTR];
#pragma unroll
    for (int k = 0; k < 15; ++k) {
      const int p = pg + 16 * k;
      if (p < NPOS) {
        const int y0 = (p * 2185) >> 15;      // p/15 exact
        const int x0 = p - y0 * 15;
        const int ym = (y0 > 0), yp = (y0 < 14), xm = (x0 > 0), xp = (x0 < 14);
        int acc = 0;
#pragma unroll
        for (int dy = 0; dy < 3; ++dy) {
          const int vy = (dy == 0) ? ym : ((dy == 2) ? yp : 1);
#pragma unroll
          for (int dx = 0; dx < 3; ++dx) {
            const int vx = (dx == 0) ? xm : ((dx == 2) ? xp : 1);
            int q = p + (dy - 1) * 15 + (dx - 1);
            q = (q < 0) ? 0 : ((q > 224) ? 224 : q);
            int kk = frow[q];
            kk = (vy && vx) ? kk : 0;
            acc += (kk * 4 * w9[dy * 3 + dx]) >> 16;   // floor(x*wq*128), exact
          }
        }
        int res = acc + bqi;
        res = res < 0 ? 0 : res;
        res = res > 32767 ? 32767 : res;
        fbuf2[cc * FSTR + p] = (unsigned short)res;
      }
    }
  }
  __syncthreads();
  // feature: ch<32 -> fbuf2, ch>=32 -> fbuf (fq identity on f)

  // ---------- Phase 3: global + regional sums (integer) ----------
  {
    int* sregKi = (int*)sreg;
    for (int task = tid; task < 576; task += 512) {
      const int r = task >> 6, c = task & 63;
      const int rh = (r * 11) >> 5;
      const int rw = r - rh * 3;
      const unsigned short* base = (c < 32) ? &fbuf2[c * FSTR] : &fbuf[c * FSTR];
      const unsigned short* fr = base + rh * 75 + rw * 5;
      int K = 0;
#pragma unroll
      for (int y = 0; y < 5; ++y)
#pragma unroll
        for (int x = 0; x < 5; ++x) K += fr[y * 15 + x];
      sregKi[task] = K;
    }
  }
  __syncthreads();
  if (tid < 64) {
    int* sregKi = (int*)sreg;
    int Ks[9], tot = 0;
#pragma unroll
    for (int r = 0; r < 9; ++r) { Ks[r] = sregKi[r * 64 + tid]; tot += Ks[r]; }
#pragma unroll
    for (int r = 0; r < 9; ++r) sreg[r * 64 + tid] = (float)(Ks[r] >> 5) * 0.0078125f;
    sfsum[tid] = (float)(tot >> 8) * 0.0078125f;
  }
  __syncthreads();   // == B0: policy path (waves 0-3) || value path (waves 4-7)

  // ---------- Seg1: policy shh | value star-up ----------
  if (tid < 64) {
    const float4* wr = (const float4*)(wsf + OFF_PW1Q + tid * 64);
    float acc = 0.f;
#pragma unroll
    for (int c4 = 0; c4 < 16; ++c4) {
      float4 w = wr[c4];
      acc += sfsum[c4 * 4 + 0] * w.x + sfsum[c4 * 4 + 1] * w.y
           + sfsum[c4 * 4 + 2] * w.z + sfsum[c4 * 4 + 3] * w.w;
    }
    shh[tid] = fmaxf(acc + wsf[OFF_PW1B + tid], 0.f);
  } else if (tid >= 256) {
    const int g = (tid >> 6) - 4;
    const int d = tid & 63;
    int ty, rA, rB, rC, rD;
    if (g == 0)      { ty = 0; rA = 0; rB = 2; rC = 6; rD = 8; }
    else if (g == 1) { ty = 1; rA = 1; rB = 3; rC = 5; rD = 7; }
    else             { ty = 2; rA = 4; rB = 4; rC = 4; rD = 4; }
    if (g < 3) {
      const float4* w1r = (const float4*)(wsf + OFF_SU1Q + ty * 4096 + d * 64);
      const float4* w2r = (const float4*)(wsf + OFF_SU2Q + ty * 4096 + d * 64);
      float aA1 = 0, aB1 = 0, aC1 = 0, aD1 = 0, aA2 = 0, aB2 = 0, aC2 = 0, aD2 = 0;
#pragma unroll 4
      for (int c4 = 0; c4 < 16; ++c4) {
        float4 w1 = w1r[c4], w2 = w2r[c4];
        float q1[4] = {w1.x, w1.y, w1.z, w1.w};
        float q2[4] = {w2.x, w2.y, w2.z, w2.w};
#pragma unroll
        for (int u = 0; u < 4; ++u) {
          const int c = c4 * 4 + u;
          float xA = sreg[rA * 64 + c], xB = sreg[rB * 64 + c];
          float xC = sreg[rC * 64 + c], xD = sreg[rD * 64 + c];
          aA1 += xA * q1[u]; aB1 += xB * q1[u]; aC1 += xC * q1[u]; aD1 += xD * q1[u];
          aA2 += xA * q2[u]; aB2 += xB * q2[u]; aC2 += xC * q2[u]; aD2 += xD * q2[u];
        }
      }
      const float bb1 = wsf[OFF_SU1B + ty * 64 + d];
      const float bb2 = wsf[OFF_SU2B + ty * 64 + d];
      hstar[rA * 64 + d] = fmaxf(aA1 + bb1, 0.f) * (aA2 + bb2);
      hstar[rB * 64 + d] = fmaxf(aB1 + bb1, 0.f) * (aB2 + bb2);
      hstar[rC * 64 + d] = fmaxf(aC1 + bb1, 0.f) * (aC2 + bb2);
      hstar[rD * 64 + d] = fmaxf(aD1 + bb1, 0.f) * (aD2 + bb2);
    }
  }
  __syncthreads();   // == B1

  // ---------- Seg2: policy o/spwq | value star-down ----------
  if (tid < 256) {
    for (int j = tid; j < 528; j += 256) {
      const float4* wr = (const float4*)(wsf + OFF_PW2Q + j * 64);
      float acc = 0.f;
#pragma unroll
      for (int c4 = 0; c4 < 16; ++c4) {
        float4 w = wr[c4];
        acc += shh[c4 * 4 + 0] * w.x + shh[c4 * 4 + 1] * w.y
             + shh[c4 * 4 + 2] * w.z + shh[c4 * 4 + 3] * w.w;
      }
      acc += wsf[OFF_PW2B + j];
      sobuf[j] = acc;
      if (j < 512)
        spwq[j] = floorf(fminf(fmaxf(acc * 16384.f, -32768.f), 32767.f)) * 6.103515625e-05f;
    }
  } else {
    const int g = (tid >> 6) - 4;
    const int d = tid & 63;
    int ty, rA, rB, rC, rD;
    if (g == 0)      { ty = 0; rA = 0; rB = 2; rC = 6; rD = 8; }
    else if (g == 1) { ty = 1; rA = 1; rB = 3; rC = 5; rD = 7; }
    else             { ty = 2; rA = 4; rB = 4; rC = 4; rD = 4; }
    if (g < 3) {
      const float4* wdr = (const float4*)(wsf + OFF_SDQ + ty * 4096 + d * 64);
      float dA = 0, dB = 0, dC = 0, dD = 0;
#pragma unroll 4
      for (int c4 = 0; c4 < 16; ++c4) {
        float4 w = wdr[c4];
        float q[4] = {w.x, w.y, w.z, w.w};
#pragma unroll
        for (int u = 0; u < 4; ++u) {
          const int c = c4 * 4 + u;
          dA += hstar[rA * 64 + c] * q[u]; dB += hstar[rB * 64 + c] * q[u];
          dC += hstar[rC * 64 + c] * q[u]; dD += hstar[rD * 64 + c] * q[u];
        }
      }
      const float bd = wsf[OFF_SDB + ty * 64 + d];
      vstar[rA * 64 + d] = dA + bd;
      vstar[rB * 64 + d] = dB + bd;
      vstar[rC * 64 + d] = dC + bd;
      vstar[rD * 64 + d] = dD + bd;
    }
  }
  __syncthreads();   // == B2

  // ---------- Seg3: policy pixel conv + out | value quads ----------
  if (tid < NPOS) {
    float pinv[32];
#pragma unroll
    for (int c = 0; c < 32; ++c) pinv[c] = (float)fbuf2[c * FSTR + tid] * 0.0078125f;
    float acc = 0.f;
#pragma unroll
    for (int i = 0; i < 16; ++i) {
      float s = 0.f;
#pragma unroll
      for (int c = 0; c < 32; ++c) s += pinv[c] * spwq[i * 32 + c];
      s = fmaxf(s + sobuf[512 + i], 0.f);
      acc += s * pout_w[i];
    }
    out[1536 + b * NPOS + tid] = acc + pout_b[0];
  } else if (tid >= 256) {
    const int g = (tid >> 6) - 4;
    const int d = tid & 63;
    int r0, r1, r2v, r3v;
    if (g == 0)      { r0 = 0; r1 = 1; r2v = 3; r3v = 4; }
    else if (g == 1) { r0 = 1; r1 = 2; r2v = 4; r3v = 5; }
    else if (g == 2) { r0 = 3; r1 = 4; r2v = 6; r3v = 7; }
    else             { r0 = 4; r1 = 5; r2v = 7; r3v = 8; }
    float a  = fq8f(vstar[r0 * 64 + d]);
    float bb = fq8f(vstar[r1 * 64 + d]);
    float cc = fq8f(vstar[r2v * 64 + d]);
    float dd = fq8f(vstar[r3v * 64 + d]);
    float ab = fq8f((a + bb + 0.0078125f) * 0.5f);
    float cd = fq8f((cc + dd + 0.0078125f) * 0.5f);
    squads[g * 64 + d] = fq8f((ab + cd + 0.0078125f) * 0.5f);
  }
  __syncthreads();   // == B3

  // ---------- Seg4: quad star up ----------
  if (tid >= 256) {
    const int g = (tid >> 6) - 4;
    const int d = tid & 63;
    const float4* w1r = (const float4*)(wsf + OFF_SU1Q + 3 * 4096 + d * 64);
    const float4* w2r = (const float4*)(wsf + OFF_SU2Q + 3 * 4096 + d * 64);
    float a1 = 0.f, a2 = 0.f;
#pragma unroll 4
    for (int c4 = 0; c4 < 16; ++c4) {
      float4 w1 = w1r[c4], w2 = w2r[c4];
      float xq0 = squads[g * 64 + c4 * 4 + 0], xq1 = squads[g * 64 + c4 * 4 + 1];
      float xq2 = squads[g * 64 + c4 * 4 + 2], xq3 = squads[g * 64 + c4 * 4 + 3];
      a1 += xq0 * w1.x + xq1 * w1.y + xq2 * w1.z + xq3 * w1.w;
      a2 += xq0 * w2.x + xq1 * w2.y + xq2 * w2.z + xq3 * w2.w;
    }
    shq[g * 64 + d] = fmaxf(a1 + wsf[OFF_SU1B + 192 + d], 0.f) * (a2 + wsf[OFF_SU2B + 192 + d]);
  }
  __syncthreads();   // == B4

  // ---------- Seg5: quad star down ----------
  if (tid >= 256) {
    const int g = (tid >> 6) - 4;
    const int d = tid & 63;
    const float4* wdr = (const float4*)(wsf + OFF_SDQ + 3 * 4096 + d * 64);
    float ad = 0.f;
#pragma unroll 4
    for (int c4 = 0; c4 < 16; ++c4) {
      float4 w = wdr[c4];
      ad += shq[g * 64 + c4 * 4 + 0] * w.x + shq[g * 64 + c4 * 4 + 1] * w.y
          + shq[g * 64 + c4 * 4 + 2] * w.z + shq[g * 64 + c4 * 4 + 3] * w.w;
    }
    svq[g * 64 + d] = ad + wsf[OFF_SDB + 192 + d];
  }
  __syncthreads();   // == B5

  // ---------- Seg6-8: value MLP [320]->64->64->3 ----------
  if (tid < 64) {
    const float4* wr = (const float4*)(wsf + OFF_VL1Q + tid * 320);
    float acc = 0.f;
#pragma unroll 4
    for (int k4 = 0; k4 < 16; ++k4) {
      float4 w = wr[k4];
      acc += sfsum[k4 * 4 + 0] * w.x + sfsum[k4 * 4 + 1] * w.y
           + sfsum[k4 * 4 + 2] * w.z + sfsum[k4 * 4 + 3] * w.w;
    }
#pragma unroll 4
    for (int k4 = 16; k4 < 80; ++k4) {
      float4 w = wr[k4];
      const int base = k4 * 4 - 64;
      acc += svq[base + 0] * w.x + svq[base + 1] * w.y
           + svq[base + 2] * w.z + svq[base + 3] * w.w;
    }
    sv1[tid] = fmaxf(acc + wsf[OFF_VL1B + tid], 0.f);
  }
  __syncthreads();
  if (tid < 64) {
    const float4* wr = (const float4*)(wsf + OFF_VL2Q + tid * 64);
    float acc = 0.f;
#pragma unroll 4
    for (int k4 = 0; k4 < 16; ++k4) {
      float4 w = wr[k4];
      acc += sv1[k4 * 4 + 0] * w.x + sv1[k4 * 4 + 1] * w.y
           + sv1[k4 * 4 + 2] * w.z + sv1[k4 * 4 + 3] * w.w;
    }
    sv2[tid] = fmaxf(acc + wsf[OFF_VL2B + tid], 0.f);
  }
  __syncthreads();
  if (tid < 3) {
    const float* wr = wsf + OFF_VL3Q + tid * 64;
    float acc = 0.f;
#pragma unroll
    for (int k = 0; k < 64; ++k) acc += sv2[k] * wr[k];
    out[b * 3 + tid] = acc + wsf[OFF_VL3B + tid];
  }
}

extern "C" void kernel_launch(void* const* d_in, const int* in_sizes, int n_in,
                              void* d_out, int out_size, void* d_ws, size_t ws_size,
                              hipStream_t stream) {
  (void)in_sizes; (void)n_in; (void)out_size; (void)ws_size;
  float* wsf = (float*)d_ws;
  int*   wsi = (int*)d_ws;
  nnue_prep<<<(WS_TOTAL + 255) / 256, 256, 0, stream>>>(
      (const float*)d_in[4],  (const float*)d_in[5],
      (const float*)d_in[6],  (const float*)d_in[7],
      (const float*)d_in[10], (const float*)d_in[11],
      (const float*)d_in[12], (const float*)d_in[13],
      (const float*)d_in[14], (const float*)d_in[15],
      (const float*)d_in[16], (const float*)d_in[17],
      (const float*)d_in[18], (const float*)d_in[19],
      (const float*)d_in[20], (const float*)d_in[21],
      (const float*)d_in[2],  (const float*)d_in[3],
      wsf, wsi);
  nnue_main<<<512, 512, 0, stream>>>(
      (const int*)d_in[0], (const float*)d_in[1],
      (const float*)d_in[8], (const float*)d_in[9],
      wsf, wsi, (float*)d_out);
}